// Round 8
// baseline (805.039 us; speedup 1.0000x reference)
//
#include <hip/hip_runtime.h>

#define NN 100000
#define NE 1600000
#define FIN 256
#define HID 64
#define NCLS 10
#define EPSF 0.3f
#define NBUCK 782   // ceil(NN/128)
#define BCAP 4096   // mean 2046, sigma ~45 -> +45 sigma headroom

typedef _Float16 f16;
typedef __attribute__((ext_vector_type(4))) _Float16 f16x4;
typedef __attribute__((ext_vector_type(8))) _Float16 f16x8;
typedef __attribute__((ext_vector_type(4))) float f32x4;

// ---------- setup kernels ----------

// split w1 [64][256] f32 -> fp16 hi/lo images (linear [h][k] layout)
__global__ void k_wt(const float* __restrict__ w1, f16* __restrict__ w_hi, f16* __restrict__ w_lo) {
    int t = blockIdx.x * 256 + threadIdx.x;
    if (t < HID * FIN) {
        float v = w1[t];
        f16 hi = (f16)v;
        f16 lo = (f16)(v - (float)hi);
        w_hi[t] = hi;
        w_lo[t] = lo;
    }
}

// phase A: scatter edges into coarse dst-buckets (sequential within bucket -> line-friendly)
__global__ void k_bucket(const int* __restrict__ ei, int* __restrict__ bcnt, int2* __restrict__ bucket) {
    int e = blockIdx.x * 256 + threadIdx.x;
    if (e < NE) {
        int s = ei[e], d = ei[NE + e];
        int b = d >> 7;
        int p = atomicAdd(&bcnt[b], 1);
        if (p < BCAP) bucket[b * BCAP + p] = make_int2(s, d);
    }
}

// phase B1: per-bucket degree count in LDS (replaces 1.6M random global atomics)
__global__ __launch_bounds__(256) void k_cnt(const int* __restrict__ bcnt, const int2* __restrict__ bucket,
                                             int* __restrict__ deg) {
    __shared__ int cnt[128];
    int b = blockIdx.x;
    if (threadIdx.x < 128) cnt[threadIdx.x] = 0;
    __syncthreads();
    int n = bcnt[b]; if (n > BCAP) n = BCAP;
    for (int t = threadIdx.x; t < n; t += 256)
        atomicAdd(&cnt[bucket[b * BCAP + t].y & 127], 1);
    __syncthreads();
    if (threadIdx.x < 128) {
        int node = b * 128 + threadIdx.x;
        if (node < NN) deg[node] = cnt[threadIdx.x];
    }
}

__global__ void k_dis(const int* __restrict__ deg, float* __restrict__ dis) {
    int i = blockIdx.x * 256 + threadIdx.x;
    if (i < NN) {
        int d = deg[i];
        dis[i] = (d > 0) ? (1.0f / sqrtf((float)d)) : 0.0f;
    }
}

// 3-kernel exclusive scan of deg -> rp (row_ptr), chunk = 1024
__global__ void k_scan1(const int* __restrict__ deg, int* __restrict__ rp, int* __restrict__ bsum) {
    __shared__ int s[1024];
    int i = blockIdx.x * 1024 + threadIdx.x;
    int v = (i < NN) ? deg[i] : 0;
    s[threadIdx.x] = v;
    __syncthreads();
    for (int off = 1; off < 1024; off <<= 1) {
        int t = (threadIdx.x >= off) ? s[threadIdx.x - off] : 0;
        __syncthreads();
        s[threadIdx.x] += t;
        __syncthreads();
    }
    if (i < NN) rp[i] = s[threadIdx.x] - v;              // exclusive
    if (threadIdx.x == 1023) bsum[blockIdx.x] = s[1023]; // block total
}

__global__ void k_scan2(int* __restrict__ bsum, int nb) {
    __shared__ int s[128];
    int v = (threadIdx.x < nb) ? bsum[threadIdx.x] : 0;
    s[threadIdx.x] = v;
    __syncthreads();
    for (int off = 1; off < 128; off <<= 1) {
        int t = (threadIdx.x >= off) ? s[threadIdx.x - off] : 0;
        __syncthreads();
        s[threadIdx.x] += t;
        __syncthreads();
    }
    if (threadIdx.x < nb) bsum[threadIdx.x] = s[threadIdx.x] - v;
}

__global__ void k_scan3(int* __restrict__ rp, const int* __restrict__ bsum) {
    int i = blockIdx.x * 1024 + threadIdx.x;
    if (i < NN) rp[i] += bsum[blockIdx.x];
    if (i == 0) rp[NN] = NE;
}

// phase B2: place src into exact CSR slot; writes confined to one ~8KB region per bucket
__global__ __launch_bounds__(256) void k_place(const int* __restrict__ bcnt, const int2* __restrict__ bucket,
                                               const int* __restrict__ rp, int* __restrict__ csr_src) {
    __shared__ int cur[128];
    int b = blockIdx.x;
    if (threadIdx.x < 128) cur[threadIdx.x] = 0;
    __syncthreads();
    int n = bcnt[b]; if (n > BCAP) n = BCAP;
    for (int t = threadIdx.x; t < n; t += 256) {
        int2 sd = bucket[b * BCAP + t];
        int p = rp[sd.y] + atomicAdd(&cur[sd.y & 127], 1);
        csr_src[p] = sd.x;
    }
}

// ---------- compute kernels ----------

// h = relu(x @ w1.T + b1) via 3-pass split-fp16 MFMA (hi*hi + lo*hi + hi*lo).
// A (x tile, 64 nodes) staged in LDS swizzled; B (w hi/lo, 64KB) read from L2.
__global__ __launch_bounds__(256) void k_gemm1(const float* __restrict__ x,
                                               const f16* __restrict__ w_hi, const f16* __restrict__ w_lo,
                                               const float* __restrict__ b1, float* __restrict__ h) {
    __shared__ f16 Ah[64 * 256];   // 32KB
    __shared__ f16 Al[64 * 256];   // 32KB
    int tid = threadIdx.x;
    int m0 = blockIdx.x * 64;

    // stage + convert x tile: thread t handles float4s at flat4 = it*256+t
#pragma unroll
    for (int it = 0; it < 16; ++it) {
        int flat4 = it * 256 + tid;
        int row = flat4 >> 6;
        int col4 = flat4 & 63;
        int grow = m0 + row; if (grow >= NN) grow = NN - 1;
        float4 xv = *reinterpret_cast<const float4*>(x + (size_t)grow * FIN + col4 * 4);
        f16x4 hi, lo;
        hi[0] = (f16)xv.x; lo[0] = (f16)(xv.x - (float)hi[0]);
        hi[1] = (f16)xv.y; lo[1] = (f16)(xv.y - (float)hi[1]);
        hi[2] = (f16)xv.z; lo[2] = (f16)(xv.z - (float)hi[2]);
        hi[3] = (f16)xv.w; lo[3] = (f16)(xv.w - (float)hi[3]);
        int hb = (col4 * 4) ^ ((row & 7) << 3);   // half-index XOR swizzle (16B granules)
        *reinterpret_cast<f16x4*>(&Ah[row * 256 + hb]) = hi;
        *reinterpret_cast<f16x4*>(&Al[row * 256 + hb]) = lo;
    }
    __syncthreads();

    int lane = tid & 63;
    int wave = tid >> 6;
    int lg = lane >> 4;    // k-group / D-row group
    int lr = lane & 15;    // A-row within tile / D-col
    int arow = wave * 16 + lr;

    f32x4 acc[4];
#pragma unroll
    for (int nt = 0; nt < 4; ++nt) acc[nt] = (f32x4){0.f, 0.f, 0.f, 0.f};

#pragma unroll
    for (int kt = 0; kt < 8; ++kt) {
        int kb = kt * 32 + lg * 8;
        int ha = arow * 256 + (kb ^ ((arow & 7) << 3));
        f16x8 a_hi = *reinterpret_cast<const f16x8*>(&Ah[ha]);
        f16x8 a_lo = *reinterpret_cast<const f16x8*>(&Al[ha]);
#pragma unroll
        for (int nt = 0; nt < 4; ++nt) {
            int bidx = (nt * 16 + lr) * 256 + kb;       // w_img [h][k] linear, L2-hot
            f16x8 b_hi = *reinterpret_cast<const f16x8*>(&w_hi[bidx]);
            f16x8 b_lo = *reinterpret_cast<const f16x8*>(&w_lo[bidx]);
            acc[nt] = __builtin_amdgcn_mfma_f32_16x16x32_f16(a_hi, b_hi, acc[nt], 0, 0, 0);
            acc[nt] = __builtin_amdgcn_mfma_f32_16x16x32_f16(a_lo, b_hi, acc[nt], 0, 0, 0);
            acc[nt] = __builtin_amdgcn_mfma_f32_16x16x32_f16(a_hi, b_lo, acc[nt], 0, 0, 0);
        }
    }

    // D: row = lg*4 + r (node), col = nt*16 + lr (hid)
#pragma unroll
    for (int nt = 0; nt < 4; ++nt) {
        int col = nt * 16 + lr;
        float bb = b1[col];
#pragma unroll
        for (int r = 0; r < 4; ++r) {
            int node = m0 + wave * 16 + lg * 4 + r;
            if (node < NN) {
                float v = fmaxf(acc[nt][r] + bb, 0.0f);
                h[(size_t)node * HID + col] = v;
            }
        }
    }
}

// layer-0 scores: wave per node, butterfly reduce
__global__ void k_alar(const float* __restrict__ h, const float* __restrict__ att_l, const float* __restrict__ att_r,
                       const float* __restrict__ dis, float2* __restrict__ aldis, float2* __restrict__ ardis) {
    int lane = threadIdx.x & 63;
    int i = blockIdx.x * 4 + (threadIdx.x >> 6);
    if (i >= NN) return;
    float hv = h[(size_t)i * HID + lane];
    float p = hv * att_l[lane];
    float q = hv * att_r[lane];
#pragma unroll
    for (int m = 1; m < 64; m <<= 1) {
        p += __shfl_xor(p, m, 64);
        q += __shfl_xor(q, m, 64);
    }
    if (lane == 0) {
        float ds = dis[i];
        aldis[i] = make_float2(p, ds);
        ardis[i] = make_float2(q, ds);
    }
}

// wave per node i. g = lane>>4 (edge subgroup), f = lane&15 (float4 feature chunk).
// coef computed per-lane at preload (tanh fused); 2-deep pipeline, 8 edges/iter.
// MODE 1: write h_out + next-layer scores. MODE 2: fused logits + log_softmax.
template <int MODE>
__global__ __launch_bounds__(256) void k_agg(const float* __restrict__ h_in, const float* __restrict__ raw,
                                             const int* __restrict__ rp, const int* __restrict__ csr_src,
                                             const float2* __restrict__ aldis_i, const float2* __restrict__ ardis_i,
                                             float* __restrict__ h_out,
                                             const float* __restrict__ att_l, const float* __restrict__ att_r,
                                             const float* __restrict__ dis,
                                             float2* __restrict__ aldis_o, float2* __restrict__ ardis_o,
                                             const float* __restrict__ w2, const float* __restrict__ b2,
                                             float* __restrict__ out) {
    int lane = threadIdx.x & 63;
    int g = lane >> 4;
    int f = lane & 15;
    int i = blockIdx.x * 4 + (threadIdx.x >> 6);
    if (i >= NN) return;
    float2 ai = ardis_i[i];  // {ar_i, dis_i} wave-uniform
    int e0 = rp[i], e1 = rp[i + 1];
    int deg = e1 - e0;

    float4 accA = make_float4(0.f, 0.f, 0.f, 0.f);
    float4 accB = make_float4(0.f, 0.f, 0.f, 0.f);

    for (int base = 0; base < deg; base += 64) {
        int rem = deg - base; if (rem > 64) rem = 64;
        int j = 0; float cf = 0.0f;
        if (lane < rem) {
            j = csr_src[e0 + base + lane];           // coalesced 4B
            float2 aj = aldis_i[j];                  // random 8B gather, 64 in flight
            cf = tanhf(aj.x + ai.x) * (aj.y * ai.y); // fused coef
        }
        for (int t = 0; t < rem; t += 8) {
            int i0 = t + g;
            int i1 = t + 4 + g;
            int s0 = i0 < rem ? i0 : rem - 1;
            int s1 = i1 < rem ? i1 : rem - 1;
            int j0 = __shfl(j, s0, 64);
            int j1 = __shfl(j, s1, 64);
            float c0 = __shfl(cf, s0, 64);
            float c1 = __shfl(cf, s1, 64);
            if (i0 >= rem) c0 = 0.0f;
            if (i1 >= rem) c1 = 0.0f;
            float4 h0 = *reinterpret_cast<const float4*>(h_in + j0 * HID + 4 * f);
            float4 h1 = *reinterpret_cast<const float4*>(h_in + j1 * HID + 4 * f);
            accA.x = fmaf(h0.x, c0, accA.x);
            accA.y = fmaf(h0.y, c0, accA.y);
            accA.z = fmaf(h0.z, c0, accA.z);
            accA.w = fmaf(h0.w, c0, accA.w);
            accB.x = fmaf(h1.x, c1, accB.x);
            accB.y = fmaf(h1.y, c1, accB.y);
            accB.z = fmaf(h1.z, c1, accB.z);
            accB.w = fmaf(h1.w, c1, accB.w);
        }
    }
    float4 acc;
    acc.x = accA.x + accB.x;
    acc.y = accA.y + accB.y;
    acc.z = accA.z + accB.z;
    acc.w = accA.w + accB.w;
#pragma unroll
    for (int m = 16; m <= 32; m <<= 1) {
        acc.x += __shfl_xor(acc.x, m, 64);
        acc.y += __shfl_xor(acc.y, m, 64);
        acc.z += __shfl_xor(acc.z, m, 64);
        acc.w += __shfl_xor(acc.w, m, 64);
    }
    float4 rawv = *reinterpret_cast<const float4*>(raw + (size_t)i * HID + 4 * f);
    acc.x = fmaf(EPSF, rawv.x, acc.x);
    acc.y = fmaf(EPSF, rawv.y, acc.y);
    acc.z = fmaf(EPSF, rawv.z, acc.z);
    acc.w = fmaf(EPSF, rawv.w, acc.w);

    if (MODE == 2) {
        float lg[NCLS];
#pragma unroll
        for (int cc = 0; cc < NCLS; cc++) {
            float4 wv = *reinterpret_cast<const float4*>(w2 + cc * HID + 4 * f);
            float p = acc.x * wv.x + acc.y * wv.y + acc.z * wv.z + acc.w * wv.w;
#pragma unroll
            for (int m = 1; m < 16; m <<= 1) p += __shfl_xor(p, m, 64);
            lg[cc] = p + b2[cc];
        }
        float mx = lg[0];
#pragma unroll
        for (int cc = 1; cc < NCLS; cc++) mx = fmaxf(mx, lg[cc]);
        float ssum = 0.0f;
#pragma unroll
        for (int cc = 0; cc < NCLS; cc++) ssum += expf(lg[cc] - mx);
        float r = mx + logf(ssum);
        if (lane < NCLS) {
            float v = 0.0f;
#pragma unroll
            for (int cc = 0; cc < NCLS; cc++)
                if (lane == cc) v = lg[cc];
            out[(size_t)i * NCLS + lane] = v - r;
        }
    } else {
        if (g == 0) *reinterpret_cast<float4*>(h_out + (size_t)i * HID + 4 * f) = acc;
        if (MODE == 1) {
            float4 alv = *reinterpret_cast<const float4*>(att_l + 4 * f);
            float4 arv = *reinterpret_cast<const float4*>(att_r + 4 * f);
            float p = acc.x * alv.x + acc.y * alv.y + acc.z * alv.z + acc.w * alv.w;
            float q = acc.x * arv.x + acc.y * arv.y + acc.z * arv.z + acc.w * arv.w;
#pragma unroll
            for (int m = 1; m < 16; m <<= 1) {
                p += __shfl_xor(p, m, 64);
                q += __shfl_xor(q, m, 64);
            }
            if (lane == 0) {
                float ds = dis[i];
                aldis_o[i] = make_float2(p, ds);
                ardis_o[i] = make_float2(q, ds);
            }
        }
    }
}

// ---------- launch ----------

extern "C" void kernel_launch(void* const* d_in, const int* in_sizes, int n_in,
                              void* d_out, int out_size, void* d_ws, size_t ws_size,
                              hipStream_t stream) {
    const float* x     = (const float*)d_in[0];
    const int*   ei    = (const int*)d_in[1];
    const float* w1    = (const float*)d_in[2];
    const float* b1    = (const float*)d_in[3];
    const float* w2    = (const float*)d_in[4];
    const float* b2    = (const float*)d_in[5];
    const float* att_l = (const float*)d_in[6];
    const float* att_r = (const float*)d_in[7];
    float* out = (float*)d_out;

    char* ws = (char*)d_ws;
    size_t off = 0;
    auto take = [&](size_t bytes) -> void* {
        void* p = ws + off;
        off += (bytes + 255) & ~(size_t)255;
        return p;
    };
    int*    deg     = (int*)take((size_t)NN * 4);
    int*    rp      = (int*)take((size_t)(NN + 1) * 4);
    int*    bsum    = (int*)take(128 * 4);
    int*    bcnt    = (int*)take((size_t)NBUCK * 4);
    float*  dis     = (float*)take((size_t)NN * 4);
    float2* aldisA  = (float2*)take((size_t)NN * 8);
    float2* ardisA  = (float2*)take((size_t)NN * 8);
    float2* aldisB  = (float2*)take((size_t)NN * 8);
    float2* ardisB  = (float2*)take((size_t)NN * 8);
    f16*    w_hi    = (f16*)take((size_t)HID * FIN * 2);
    f16*    w_lo    = (f16*)take((size_t)HID * FIN * 2);
    int2*   bucket  = (int2*)take((size_t)NBUCK * BCAP * 8);
    int*    csr_src = (int*)take((size_t)NE * 4);
    float*  hA      = (float*)take((size_t)NN * HID * 4);
    float*  hB      = (float*)take((size_t)NN * HID * 4);

    hipMemsetAsync(bcnt, 0, (size_t)NBUCK * 4, stream);

    const int EB = (NE + 255) / 256;
    const int NB = (NN + 255) / 256;
    const int SB = (NN + 1023) / 1024;  // 98

    k_wt<<<64, 256, 0, stream>>>(w1, w_hi, w_lo);
    k_bucket<<<EB, 256, 0, stream>>>(ei, bcnt, bucket);
    k_cnt<<<NBUCK, 256, 0, stream>>>(bcnt, bucket, deg);
    k_dis<<<NB, 256, 0, stream>>>(deg, dis);
    k_scan1<<<SB, 1024, 0, stream>>>(deg, rp, bsum);
    k_scan2<<<1, 128, 0, stream>>>(bsum, SB);
    k_scan3<<<SB, 1024, 0, stream>>>(rp, bsum);
    k_place<<<NBUCK, 256, 0, stream>>>(bcnt, bucket, rp, csr_src);

    // lin1 + ReLU (MFMA split-fp16)
    k_gemm1<<<(NN + 63) / 64, 256, 0, stream>>>(x, w_hi, w_lo, b1, hA);
    // layer-0 scores
    k_alar<<<NN / 4, 256, 0, stream>>>(hA, att_l, att_r, dis, aldisA, ardisA);

    // layer 0: in hA (scores A), raw hA -> hB, fused layer-1 scores -> B buffers
    k_agg<1><<<NN / 4, 256, 0, stream>>>(hA, hA, rp, csr_src, aldisA, ardisA, hB,
                                         att_l + HID, att_r + HID, dis, aldisB, ardisB,
                                         nullptr, nullptr, nullptr);

    // layer 1: in hB (scores B), raw hA -> fused logits/log_softmax -> out
    k_agg<2><<<NN / 4, 256, 0, stream>>>(hB, hA, rp, csr_src, aldisB, ardisB, nullptr,
                                         nullptr, nullptr, nullptr, nullptr, nullptr,
                                         w2, b2, out);
}

// Round 10
// 563.048 us; speedup vs baseline: 1.4298x; 1.4298x over previous
//
#include <hip/hip_runtime.h>

#define NN 100000
#define NE 1600000
#define FIN 256
#define HID 64
#define NCLS 10
#define EPSF 0.3f

typedef _Float16 f16;
typedef __attribute__((ext_vector_type(4))) _Float16 f16x4;
typedef __attribute__((ext_vector_type(8))) _Float16 f16x8;
typedef __attribute__((ext_vector_type(4))) float f32x4;

// ---------- setup kernels ----------

// split w1 [64][256] f32 -> fp16 hi/lo images (linear [h][k] layout)
__global__ void k_wt(const float* __restrict__ w1, f16* __restrict__ w_hi, f16* __restrict__ w_lo) {
    int t = blockIdx.x * 256 + threadIdx.x;
    if (t < HID * FIN) {
        float v = w1[t];
        f16 hi = (f16)v;
        f16 lo = (f16)(v - (float)hi);
        w_hi[t] = hi;
        w_lo[t] = lo;
    }
}

// degree histogram: 1.6M atomics over 100k counters (~16 deep) -- low contention
__global__ void k_deg(const int* __restrict__ ei, int* __restrict__ deg) {
    int e = blockIdx.x * 256 + threadIdx.x;
    if (e < NE) atomicAdd(&deg[ei[NE + e]], 1);
}

__global__ void k_dis(const int* __restrict__ deg, float* __restrict__ dis) {
    int i = blockIdx.x * 256 + threadIdx.x;
    if (i < NN) {
        int d = deg[i];
        dis[i] = (d > 0) ? (1.0f / sqrtf((float)d)) : 0.0f;
    }
}

// 3-kernel exclusive scan of deg -> rp (row_ptr), chunk = 1024
__global__ void k_scan1(const int* __restrict__ deg, int* __restrict__ rp, int* __restrict__ bsum) {
    __shared__ int s[1024];
    int i = blockIdx.x * 1024 + threadIdx.x;
    int v = (i < NN) ? deg[i] : 0;
    s[threadIdx.x] = v;
    __syncthreads();
    for (int off = 1; off < 1024; off <<= 1) {
        int t = (threadIdx.x >= off) ? s[threadIdx.x - off] : 0;
        __syncthreads();
        s[threadIdx.x] += t;
        __syncthreads();
    }
    if (i < NN) rp[i] = s[threadIdx.x] - v;              // exclusive
    if (threadIdx.x == 1023) bsum[blockIdx.x] = s[1023]; // block total
}

__global__ void k_scan2(int* __restrict__ bsum, int nb) {
    __shared__ int s[128];
    int v = (threadIdx.x < nb) ? bsum[threadIdx.x] : 0;
    s[threadIdx.x] = v;
    __syncthreads();
    for (int off = 1; off < 128; off <<= 1) {
        int t = (threadIdx.x >= off) ? s[threadIdx.x - off] : 0;
        __syncthreads();
        s[threadIdx.x] += t;
        __syncthreads();
    }
    if (threadIdx.x < nb) bsum[threadIdx.x] = s[threadIdx.x] - v;
}

__global__ void k_scan3(int* __restrict__ rp, const int* __restrict__ bsum) {
    int i = blockIdx.x * 1024 + threadIdx.x;
    if (i < NN) rp[i] += bsum[blockIdx.x];
    if (i == 0) rp[NN] = NE;
}

// direct scatter with per-node cursors (low contention); NT store to reduce line RMW
__global__ void k_fill(const int* __restrict__ ei, const int* __restrict__ rp,
                       int* __restrict__ cursor, int* __restrict__ csr_src) {
    int e = blockIdx.x * 256 + threadIdx.x;
    if (e < NE) {
        int s = ei[e], d = ei[NE + e];
        int pos = rp[d] + atomicAdd(&cursor[d], 1);
        __builtin_nontemporal_store(s, &csr_src[pos]);
    }
}

// ---------- compute kernels ----------

// h = relu(x @ w1.T + b1) via 3-pass split-fp16 MFMA (hi*hi + lo*hi + hi*lo).
// A (x tile, 64 nodes) staged in LDS swizzled; B (w hi/lo, 64KB) read from L2.
// Epilogue: layer-0 scores al/ar from the D fragments (16-lane group reduce).
__global__ __launch_bounds__(256) void k_gemm1(const float* __restrict__ x,
                                               const f16* __restrict__ w_hi, const f16* __restrict__ w_lo,
                                               const float* __restrict__ b1, const float* __restrict__ dis,
                                               const float* __restrict__ att_l0, const float* __restrict__ att_r0,
                                               float* __restrict__ h,
                                               float2* __restrict__ aldis, float2* __restrict__ ardis) {
    __shared__ f16 Ah[64 * 256];   // 32KB
    __shared__ f16 Al[64 * 256];   // 32KB
    int tid = threadIdx.x;
    int m0 = blockIdx.x * 64;

    // stage + convert x tile: thread t handles float4s at flat4 = it*256+t
#pragma unroll
    for (int it = 0; it < 16; ++it) {
        int flat4 = it * 256 + tid;
        int row = flat4 >> 6;
        int col4 = flat4 & 63;
        int grow = m0 + row; if (grow >= NN) grow = NN - 1;
        float4 xv = *reinterpret_cast<const float4*>(x + (size_t)grow * FIN + col4 * 4);
        f16x4 hi, lo;
        hi[0] = (f16)xv.x; lo[0] = (f16)(xv.x - (float)hi[0]);
        hi[1] = (f16)xv.y; lo[1] = (f16)(xv.y - (float)hi[1]);
        hi[2] = (f16)xv.z; lo[2] = (f16)(xv.z - (float)hi[2]);
        hi[3] = (f16)xv.w; lo[3] = (f16)(xv.w - (float)hi[3]);
        int hb = (col4 * 4) ^ ((row & 7) << 3);   // half-index XOR swizzle (16B granules)
        *reinterpret_cast<f16x4*>(&Ah[row * 256 + hb]) = hi;
        *reinterpret_cast<f16x4*>(&Al[row * 256 + hb]) = lo;
    }
    __syncthreads();

    int lane = tid & 63;
    int wave = tid >> 6;
    int lg = lane >> 4;    // k-group / D-row group
    int lr = lane & 15;    // A-row within tile / D-col
    int arow = wave * 16 + lr;

    f32x4 acc[4];
#pragma unroll
    for (int nt = 0; nt < 4; ++nt) acc[nt] = (f32x4){0.f, 0.f, 0.f, 0.f};

#pragma unroll
    for (int kt = 0; kt < 8; ++kt) {
        int kb = kt * 32 + lg * 8;
        int ha = arow * 256 + (kb ^ ((arow & 7) << 3));
        f16x8 a_hi = *reinterpret_cast<const f16x8*>(&Ah[ha]);
        f16x8 a_lo = *reinterpret_cast<const f16x8*>(&Al[ha]);
#pragma unroll
        for (int nt = 0; nt < 4; ++nt) {
            int bidx = (nt * 16 + lr) * 256 + kb;       // w_img [h][k] linear, L2-hot
            f16x8 b_hi = *reinterpret_cast<const f16x8*>(&w_hi[bidx]);
            f16x8 b_lo = *reinterpret_cast<const f16x8*>(&w_lo[bidx]);
            acc[nt] = __builtin_amdgcn_mfma_f32_16x16x32_f16(a_hi, b_hi, acc[nt], 0, 0, 0);
            acc[nt] = __builtin_amdgcn_mfma_f32_16x16x32_f16(a_lo, b_hi, acc[nt], 0, 0, 0);
            acc[nt] = __builtin_amdgcn_mfma_f32_16x16x32_f16(a_hi, b_lo, acc[nt], 0, 0, 0);
        }
    }

    // D: row = lg*4 + r (node), col = nt*16 + lr (hid)
    float hv[4][4];
#pragma unroll
    for (int nt = 0; nt < 4; ++nt) {
        int col = nt * 16 + lr;
        float bb = b1[col];
#pragma unroll
        for (int r = 0; r < 4; ++r) {
            float v = fmaxf(acc[nt][r] + bb, 0.0f);
            hv[nt][r] = v;
            int node = m0 + wave * 16 + lg * 4 + r;
            if (node < NN) h[(size_t)node * HID + col] = v;
        }
    }

    // fused layer-0 scores: for each of this lane's 4 nodes, partial dot over its 4 cols,
    // then reduce across the 16-lane group (lanes with same lg are contiguous).
    float attl[4], attr[4];
#pragma unroll
    for (int nt = 0; nt < 4; ++nt) {
        attl[nt] = att_l0[nt * 16 + lr];
        attr[nt] = att_r0[nt * 16 + lr];
    }
#pragma unroll
    for (int r = 0; r < 4; ++r) {
        float p = 0.0f, q = 0.0f;
#pragma unroll
        for (int nt = 0; nt < 4; ++nt) {
            p = fmaf(hv[nt][r], attl[nt], p);
            q = fmaf(hv[nt][r], attr[nt], q);
        }
#pragma unroll
        for (int m = 1; m < 16; m <<= 1) {
            p += __shfl_xor(p, m, 64);
            q += __shfl_xor(q, m, 64);
        }
        int node = m0 + wave * 16 + lg * 4 + r;
        if (lr == 0 && node < NN) {
            float ds = dis[node];
            aldis[node] = make_float2(p, ds);
            ardis[node] = make_float2(q, ds);
        }
    }
}

// wave per node i. g = lane>>4 (edge subgroup), f = lane&15 (float4 feature chunk).
// coef computed per-lane at preload (tanh fused); 2-deep pipeline, 8 edges/iter.
// MODE 1: write h_out + next-layer scores. MODE 2: fused logits + log_softmax.
template <int MODE>
__global__ __launch_bounds__(256) void k_agg(const float* __restrict__ h_in, const float* __restrict__ raw,
                                             const int* __restrict__ rp, const int* __restrict__ csr_src,
                                             const float2* __restrict__ aldis_i, const float2* __restrict__ ardis_i,
                                             float* __restrict__ h_out,
                                             const float* __restrict__ att_l, const float* __restrict__ att_r,
                                             const float* __restrict__ dis,
                                             float2* __restrict__ aldis_o, float2* __restrict__ ardis_o,
                                             const float* __restrict__ w2, const float* __restrict__ b2,
                                             float* __restrict__ out) {
    int lane = threadIdx.x & 63;
    int g = lane >> 4;
    int f = lane & 15;
    int i = blockIdx.x * 4 + (threadIdx.x >> 6);
    if (i >= NN) return;
    float2 ai = ardis_i[i];  // {ar_i, dis_i} wave-uniform
    int e0 = rp[i], e1 = rp[i + 1];
    int deg = e1 - e0;

    float4 accA = make_float4(0.f, 0.f, 0.f, 0.f);
    float4 accB = make_float4(0.f, 0.f, 0.f, 0.f);

    for (int base = 0; base < deg; base += 64) {
        int rem = deg - base; if (rem > 64) rem = 64;
        int j = 0; float cf = 0.0f;
        if (lane < rem) {
            j = csr_src[e0 + base + lane];           // coalesced 4B
            float2 aj = aldis_i[j];                  // random 8B gather, 64 in flight
            cf = tanhf(aj.x + ai.x) * (aj.y * ai.y); // fused coef
        }
        for (int t = 0; t < rem; t += 8) {
            int i0 = t + g;
            int i1 = t + 4 + g;
            int s0 = i0 < rem ? i0 : rem - 1;
            int s1 = i1 < rem ? i1 : rem - 1;
            int j0 = __shfl(j, s0, 64);
            int j1 = __shfl(j, s1, 64);
            float c0 = __shfl(cf, s0, 64);
            float c1 = __shfl(cf, s1, 64);
            if (i0 >= rem) c0 = 0.0f;
            if (i1 >= rem) c1 = 0.0f;
            float4 h0 = *reinterpret_cast<const float4*>(h_in + j0 * HID + 4 * f);
            float4 h1 = *reinterpret_cast<const float4*>(h_in + j1 * HID + 4 * f);
            accA.x = fmaf(h0.x, c0, accA.x);
            accA.y = fmaf(h0.y, c0, accA.y);
            accA.z = fmaf(h0.z, c0, accA.z);
            accA.w = fmaf(h0.w, c0, accA.w);
            accB.x = fmaf(h1.x, c1, accB.x);
            accB.y = fmaf(h1.y, c1, accB.y);
            accB.z = fmaf(h1.z, c1, accB.z);
            accB.w = fmaf(h1.w, c1, accB.w);
        }
    }
    float4 acc;
    acc.x = accA.x + accB.x;
    acc.y = accA.y + accB.y;
    acc.z = accA.z + accB.z;
    acc.w = accA.w + accB.w;
#pragma unroll
    for (int m = 16; m <= 32; m <<= 1) {
        acc.x += __shfl_xor(acc.x, m, 64);
        acc.y += __shfl_xor(acc.y, m, 64);
        acc.z += __shfl_xor(acc.z, m, 64);
        acc.w += __shfl_xor(acc.w, m, 64);
    }
    float4 rawv = *reinterpret_cast<const float4*>(raw + (size_t)i * HID + 4 * f);
    acc.x = fmaf(EPSF, rawv.x, acc.x);
    acc.y = fmaf(EPSF, rawv.y, acc.y);
    acc.z = fmaf(EPSF, rawv.z, acc.z);
    acc.w = fmaf(EPSF, rawv.w, acc.w);

    if (MODE == 2) {
        float lg[NCLS];
#pragma unroll
        for (int cc = 0; cc < NCLS; cc++) {
            float4 wv = *reinterpret_cast<const float4*>(w2 + cc * HID + 4 * f);
            float p = acc.x * wv.x + acc.y * wv.y + acc.z * wv.z + acc.w * wv.w;
#pragma unroll
            for (int m = 1; m < 16; m <<= 1) p += __shfl_xor(p, m, 64);
            lg[cc] = p + b2[cc];
        }
        float mx = lg[0];
#pragma unroll
        for (int cc = 1; cc < NCLS; cc++) mx = fmaxf(mx, lg[cc]);
        float ssum = 0.0f;
#pragma unroll
        for (int cc = 0; cc < NCLS; cc++) ssum += expf(lg[cc] - mx);
        float r = mx + logf(ssum);
        if (lane < NCLS) {
            float v = 0.0f;
#pragma unroll
            for (int cc = 0; cc < NCLS; cc++)
                if (lane == cc) v = lg[cc];
            out[(size_t)i * NCLS + lane] = v - r;
        }
    } else {
        if (g == 0) *reinterpret_cast<float4*>(h_out + (size_t)i * HID + 4 * f) = acc;
        if (MODE == 1) {
            float4 alv = *reinterpret_cast<const float4*>(att_l + 4 * f);
            float4 arv = *reinterpret_cast<const float4*>(att_r + 4 * f);
            float p = acc.x * alv.x + acc.y * alv.y + acc.z * alv.z + acc.w * alv.w;
            float q = acc.x * arv.x + acc.y * arv.y + acc.z * arv.z + acc.w * arv.w;
#pragma unroll
            for (int m = 1; m < 16; m <<= 1) {
                p += __shfl_xor(p, m, 64);
                q += __shfl_xor(q, m, 64);
            }
            if (lane == 0) {
                float ds = dis[i];
                aldis_o[i] = make_float2(p, ds);
                ardis_o[i] = make_float2(q, ds);
            }
        }
    }
}

// ---------- launch ----------

extern "C" void kernel_launch(void* const* d_in, const int* in_sizes, int n_in,
                              void* d_out, int out_size, void* d_ws, size_t ws_size,
                              hipStream_t stream) {
    const float* x     = (const float*)d_in[0];
    const int*   ei    = (const int*)d_in[1];
    const float* w1    = (const float*)d_in[2];
    const float* b1    = (const float*)d_in[3];
    const float* w2    = (const float*)d_in[4];
    const float* b2    = (const float*)d_in[5];
    const float* att_l = (const float*)d_in[6];
    const float* att_r = (const float*)d_in[7];
    float* out = (float*)d_out;

    char* ws = (char*)d_ws;
    size_t off = 0;
    auto take = [&](size_t bytes) -> void* {
        void* p = ws + off;
        off += (bytes + 255) & ~(size_t)255;
        return p;
    };
    int*    deg     = (int*)take((size_t)NN * 4);
    int*    cursor  = (int*)take((size_t)NN * 4);
    int*    rp      = (int*)take((size_t)(NN + 1) * 4);
    int*    bsum    = (int*)take(128 * 4);
    float*  dis     = (float*)take((size_t)NN * 4);
    float2* aldisA  = (float2*)take((size_t)NN * 8);
    float2* ardisA  = (float2*)take((size_t)NN * 8);
    float2* aldisB  = (float2*)take((size_t)NN * 8);
    float2* ardisB  = (float2*)take((size_t)NN * 8);
    f16*    w_hi    = (f16*)take((size_t)HID * FIN * 2);
    f16*    w_lo    = (f16*)take((size_t)HID * FIN * 2);
    int*    csr_src = (int*)take((size_t)NE * 4);
    float*  hA      = (float*)take((size_t)NN * HID * 4);
    float*  hB      = (float*)take((size_t)NN * HID * 4);

    hipMemsetAsync(deg, 0, (size_t)NN * 4, stream);
    hipMemsetAsync(cursor, 0, (size_t)NN * 4, stream);

    const int EB = (NE + 255) / 256;
    const int NB = (NN + 255) / 256;
    const int SB = (NN + 1023) / 1024;  // 98

    k_wt<<<64, 256, 0, stream>>>(w1, w_hi, w_lo);
    k_deg<<<EB, 256, 0, stream>>>(ei, deg);
    k_dis<<<NB, 256, 0, stream>>>(deg, dis);
    k_scan1<<<SB, 1024, 0, stream>>>(deg, rp, bsum);
    k_scan2<<<1, 128, 0, stream>>>(bsum, SB);
    k_scan3<<<SB, 1024, 0, stream>>>(rp, bsum);
    k_fill<<<EB, 256, 0, stream>>>(ei, rp, cursor, csr_src);

    // lin1 + ReLU (MFMA split-fp16) + fused layer-0 scores -> A buffers
    k_gemm1<<<(NN + 63) / 64, 256, 0, stream>>>(x, w_hi, w_lo, b1, dis, att_l, att_r,
                                                hA, aldisA, ardisA);

    // layer 0: in hA (scores A), raw hA -> hB, fused layer-1 scores -> B buffers
    k_agg<1><<<NN / 4, 256, 0, stream>>>(hA, hA, rp, csr_src, aldisA, ardisA, hB,
                                         att_l + HID, att_r + HID, dis, aldisB, ardisB,
                                         nullptr, nullptr, nullptr);

    // layer 1: in hB (scores B), raw hA -> fused logits/log_softmax -> out
    k_agg<2><<<NN / 4, 256, 0, stream>>>(hB, hA, rp, csr_src, aldisB, ardisB, nullptr,
                                         nullptr, nullptr, nullptr, nullptr, nullptr,
                                         w2, b2, out);
}